// Round 1
// 220.688 us; speedup vs baseline: 1.1150x; 1.1150x over previous
//
#include <hip/hip_runtime.h>
#include <hip/hip_bf16.h>
#include <stdint.h>

// Problem constants
#define T_TOK 8192   // B*S tokens
#define HID   2048
#define OUTD  2048
#define NE    8
#define RR    16
#define KAUG  2176   // 2048 + NE*RR
#define NH    128    // h columns (NE*RR)

typedef __bf16 bf16x8 __attribute__((ext_vector_type(8)));
typedef float  f32x4  __attribute__((ext_vector_type(4)));

#define AS1(p) ((__attribute__((address_space(1))) void*)(p))
#define AS3(p) ((__attribute__((address_space(3))) void*)(p))

__device__ inline unsigned short f2bf(float f) {
  unsigned int u = __builtin_bit_cast(unsigned int, f);
  unsigned int r = (u + 0x7fffu + ((u >> 16) & 1u)) >> 16;   // RNE
  return (unsigned short)r;
}

__device__ inline ushort4 f2bf4(float4 v) {
  ushort4 u;
  u.x = f2bf(v.x); u.y = f2bf(v.y); u.z = f2bf(v.z); u.w = f2bf(v.w);
  return u;
}

// ---- fused prep ----
// blocks [0,1024):   x -> bf16 Xa[:,0:2048] + exact fp64 router -> wte[t][8]
//                    (one wave per token, 8 tokens/block; gw staged in LDS fp32
//                     -> cuts gw L2 traffic 512MB -> 64MB; math bit-identical)
// blocks [1024,3328): weight converts (W,B -> Wa augmented; A -> Ag), verbatim
//                    per-thread bodies from the proven k_wba, re-indexed to 512 thr.
__global__ __launch_bounds__(512) void k_prep(const float* __restrict__ x,
                                              const float* __restrict__ gw,
                                              const float* __restrict__ W,
                                              const float* __restrict__ Bw,
                                              const float* __restrict__ A,
                                              unsigned short* __restrict__ Xa,
                                              float* __restrict__ wte,
                                              unsigned short* __restrict__ Wa,
                                              unsigned short* __restrict__ Ag) {
  __shared__ float gws[NE * HID];     // 64 KiB
  if (blockIdx.x < 1024) {
    // cooperative gw stage: 512 threads x 8 float4 = 16384 floats
#pragma unroll
    for (int i = 0; i < 8; ++i) {
      int idx = (i * 512 + (int)threadIdx.x) * 4;
      *(float4*)(gws + idx) = *(const float4*)(gw + idx);
    }
    __syncthreads();
    int w = threadIdx.x >> 6, lane = threadIdx.x & 63;
    int t = blockIdx.x * 8 + w;
    const float* xt = x + (size_t)t * HID;
    unsigned short* xo = Xa + (size_t)t * KAUG;
    double acc[8] = {0, 0, 0, 0, 0, 0, 0, 0};
#pragma unroll
    for (int i = 0; i < 8; ++i) {
      int k = (i * 64 + lane) * 4;
      float4 xv = *(const float4*)(xt + k);
      *(ushort4*)(xo + k) = f2bf4(xv);
#pragma unroll
      for (int e = 0; e < 8; ++e) {
        float4 gv = *(const float4*)(gws + e * HID + k);   // LDS, values identical to global
        acc[e] += (double)xv.x * gv.x + (double)xv.y * gv.y +
                  (double)xv.z * gv.z + (double)xv.w * gv.w;
      }
    }
#pragma unroll
    for (int off = 32; off >= 1; off >>= 1)
#pragma unroll
      for (int e = 0; e < 8; ++e)
        acc[e] += __shfl_down(acc[e], off, 64);
    if (lane == 0) {
      int e0 = 0; double l0 = acc[0];
#pragma unroll
      for (int e = 1; e < 8; ++e) if (acc[e] > l0) { l0 = acc[e]; e0 = e; }
      int e1 = -1; double l1 = -1e300;
#pragma unroll
      for (int e = 0; e < 8; ++e) if (e != e0 && acc[e] > l1) { l1 = acc[e]; e1 = e; }
      double w0 = 16.0 / (1.0 + exp(l1 - l0));
      float o[8] = {0.f, 0.f, 0.f, 0.f, 0.f, 0.f, 0.f, 0.f};
      o[e0] = (float)w0;
      o[e1] = (float)(16.0 - w0);
      float4* p = (float4*)(wte + (size_t)t * 8);
      p[0] = make_float4(o[0], o[1], o[2], o[3]);
      p[1] = make_float4(o[4], o[5], o[6], o[7]);
    }
  } else {
    int b2 = blockIdx.x - 1024;
    if (b2 < 2048) {
      int tid = b2 * 512 + threadIdx.x;
      int row = tid >> 9, c = (tid & 511) << 2;
      float4 v = *(const float4*)(W + (size_t)row * HID + c);
      *(ushort4*)(Wa + (size_t)row * KAUG + c) = f2bf4(v);
    } else if (b2 < 2176) {
      int tid = (b2 - 2048) * 512 + threadIdx.x;
      int o = tid >> 5, j = (tid & 31) << 2;
      int e = j >> 4, r = j & 15;
      float4 v = *(const float4*)(Bw + (size_t)e * OUTD * RR + (size_t)o * RR + r);
      *(ushort4*)(Wa + (size_t)o * KAUG + 2048 + j) = f2bf4(v);
    } else {
      int tid = (b2 - 2176) * 512 + threadIdx.x;
      float4 v = *(const float4*)(A + (size_t)tid * 4);
      *(ushort4*)(Ag + (size_t)tid * 4) = f2bf4(v);
    }
  }
}

// ---- fused h-GEMM + router scale: writes bf16 aug cols of Xa directly ----
// Ring-of-4 counted-vmcnt pipeline (prefetch depth 3, vmcnt(6), raw s_barrier):
// replaces the per-tile vmcnt(0) drain that made this kernel latency-bound at
// 2 blocks/CU. Race-free: a slot is re-staged only after the block barrier
// following its last read; vmcnt(N)+barrier before compute guarantees the
// tile landed in every wave. Arithmetic identical to the proven version.
__global__ __launch_bounds__(256) void k_ha(const unsigned short* __restrict__ Xa,
                                            const unsigned short* __restrict__ Ag,
                                            const float* __restrict__ wte,
                                            unsigned short* __restrict__ XaW) {
  __shared__ unsigned short Xs[4][32 * 64];   // 4 x 4 KiB
  __shared__ unsigned short As[4][64 * 64];   // 4 x 8 KiB  (48 KiB total)
  int tm = (blockIdx.x >> 1) * 32;
  int ch = (blockIdx.x & 1) * 64;       // column half of the 128 h-cols
  int w = threadIdx.x >> 6, lane = threadIdx.x & 63;
  int lrow = lane >> 3;
  int lcol_s = (lane & 7) << 3;                       // LDS dest (forced contiguous)
  int lcol_g = ((lane & 7) ^ (lrow & 7)) << 3;        // swizzled global source

  const unsigned short* gX = Xa + (size_t)(tm + w * 8 + lrow) * KAUG + lcol_g;
  const unsigned short* gA = Ag + (size_t)(ch + w * 16 + lrow) * HID + lcol_g;
  int sxo = (w * 8 + lrow) * 64 + lcol_s;
  int sao = (w * 16 + lrow) * 64 + lcol_s;

  f32x4 acc[2] = {};

#define HA_STAGE(slot, koff) do {                                                         \
    __builtin_amdgcn_global_load_lds(AS1(gX + (koff)), AS3(&Xs[slot][0] + sxo), 16, 0, 0);\
    __builtin_amdgcn_global_load_lds(AS1(gA + (koff)), AS3(&As[slot][0] + sao), 16, 0, 0);\
    __builtin_amdgcn_global_load_lds(AS1(gA + (size_t)8 * HID + (koff)),                  \
                                     AS3(&As[slot][0] + 8 * 64 + sao), 16, 0, 0);         \
  } while (0)

#define HA_COMP(s) do {                                                                   \
    _Pragma("unroll")                                                                     \
    for (int ks = 0; ks < 2; ++ks) {                                                      \
      int kch = ks * 4 + (lane >> 4);                                                     \
      int ko = ((kch ^ (lane & 7)) << 3);             /* swizzled read offset */          \
      bf16x8 a = *(const bf16x8*)(&Xs[s][0] + ((w >> 1) * 16 + (lane & 15)) * 64 + ko);   \
      _Pragma("unroll")                                                                   \
      for (int fn = 0; fn < 2; ++fn) {                                                    \
        bf16x8 bv = *(const bf16x8*)(&As[s][0] + ((w & 1) * 32 + fn * 16 + (lane & 15)) * 64 + ko); \
        acc[fn] = __builtin_amdgcn_mfma_f32_16x16x32_bf16(a, bv, acc[fn], 0, 0, 0);       \
      }                                                                                   \
    }                                                                                     \
  } while (0)

  // prologue: tiles 0,1,2 in flight (9 loads/wave)
  HA_STAGE(0, 0);
  HA_STAGE(1, 64);
  HA_STAGE(2, 128);
  // main: 32 tiles total (HID/64); stage tile t+3 after the post-compute barrier
  for (int t = 0; t < 29; ++t) {
    asm volatile("s_waitcnt vmcnt(6)" ::: "memory");   // tiles t+1,t+2 may stay in flight
    __builtin_amdgcn_s_barrier();                      // all waves' tile-t loads landed
    HA_COMP(t & 3);
    __builtin_amdgcn_s_barrier();                      // all reads of slot (t+3)&3 long done
    HA_STAGE((t + 3) & 3, (t + 3) * 64);
  }
  // tail: tiles 29,30,31 (no further stages; tighten vmcnt)
  asm volatile("s_waitcnt vmcnt(6)" ::: "memory");
  __builtin_amdgcn_s_barrier();
  HA_COMP(1);                                          // 29 & 3
  asm volatile("s_waitcnt vmcnt(3)" ::: "memory");
  __builtin_amdgcn_s_barrier();
  HA_COMP(2);                                          // 30 & 3
  asm volatile("s_waitcnt vmcnt(0)" ::: "memory");
  __builtin_amdgcn_s_barrier();
  HA_COMP(3);                                          // 31 & 3
#undef HA_STAGE
#undef HA_COMP

  int q = lane >> 4;
#pragma unroll
  for (int fn = 0; fn < 2; ++fn) {
    int col = ch + (w & 1) * 32 + fn * 16 + (lane & 15);
    int e = col >> 4;
#pragma unroll
    for (int r = 0; r < 4; ++r) {
      int t = tm + (w >> 1) * 16 + q * 4 + r;
      float we = wte[(size_t)t * 8 + e];
      XaW[(size_t)t * KAUG + 2048 + col] = f2bf(we * acc[fn][r]);
    }
  }
}

// ---- main GEMM: out[t][o] = sum_{k<2176} Xa[t][k]*Wa[o][k] ----
// m97 structure + XOR-swizzled LDS + XCD swizzle. UNCHANGED (proven 76 us / 960 TF).
// __launch_bounds__(256,4): cap regs at 128/thread (64 VGPR + 64 AGPR acc)
// so all 4 blocks/CU (grid 1024 = 4x256) are co-resident -> no 3+1 tail.
__global__ __launch_bounds__(256, 4) void k_gemm(const unsigned short* __restrict__ Xa,
                                                 const unsigned short* __restrict__ Wa,
                                                 float* __restrict__ out) {
  __shared__ unsigned short As[128 * 64];
  __shared__ unsigned short Bs[128 * 64];
  int lid = blockIdx.x;                 // grid = 1024 linear
  int xcd = lid & 7, s = lid >> 3;
  int bm = (xcd * 8 + (s & 7)) * 128;   // 0..63
  int bn = (s >> 3) * 128;              // 0..15
  int w = threadIdx.x >> 6, lane = threadIdx.x & 63;
  int wm = (w >> 1) * 64, wn = (w & 1) * 64;
  int lrow = lane >> 3;
  int lcol_s = (lane & 7) << 3;
  int lcol_g = ((lane & 7) ^ (lrow & 7)) << 3;

  const unsigned short* gA = Xa + (size_t)(bm + w * 32 + lrow) * KAUG + lcol_g;
  const unsigned short* gB = Wa + (size_t)(bn + w * 32 + lrow) * KAUG + lcol_g;
  unsigned short* sA = As + (w * 32 + lrow) * 64 + lcol_s;
  unsigned short* sB = Bs + (w * 32 + lrow) * 64 + lcol_s;

  f32x4 acc[4][4] = {};
  for (int kt = 0; kt < KAUG; kt += 64) {
#pragma unroll
    for (int i = 0; i < 4; ++i) {
      __builtin_amdgcn_global_load_lds(AS1(gA + (size_t)i * 8 * KAUG), AS3(sA + i * 8 * 64), 16, 0, 0);
      __builtin_amdgcn_global_load_lds(AS1(gB + (size_t)i * 8 * KAUG), AS3(sB + i * 8 * 64), 16, 0, 0);
    }
    __syncthreads();
#pragma unroll
    for (int ks = 0; ks < 2; ++ks) {
      int kch = ks * 4 + (lane >> 4);
      int ko = ((kch ^ (lane & 7)) << 3);             // swizzled read offset
      bf16x8 a[4], b[4];
#pragma unroll
      for (int f = 0; f < 4; ++f) a[f] = *(const bf16x8*)(As + (wm + f * 16 + (lane & 15)) * 64 + ko);
#pragma unroll
      for (int f = 0; f < 4; ++f) b[f] = *(const bf16x8*)(Bs + (wn + f * 16 + (lane & 15)) * 64 + ko);
#pragma unroll
      for (int fm = 0; fm < 4; ++fm)
#pragma unroll
        for (int fn = 0; fn < 4; ++fn)
          acc[fm][fn] = __builtin_amdgcn_mfma_f32_16x16x32_bf16(a[fm], b[fn], acc[fm][fn], 0, 0, 0);
    }
    __syncthreads();
    gA += 64; gB += 64;
  }
#pragma unroll
  for (int fm = 0; fm < 4; ++fm) {
    int row = bm + wm + fm * 16 + ((lane >> 4) << 2);
#pragma unroll
    for (int r = 0; r < 4; ++r) {
      float* orow = out + (size_t)(row + r) * OUTD + bn + wn + (lane & 15);
#pragma unroll
      for (int fn = 0; fn < 4; ++fn) orow[fn * 16] = acc[fm][fn][r];
    }
  }
}

extern "C" void kernel_launch(void* const* d_in, const int* in_sizes, int n_in,
                              void* d_out, int out_size, void* d_ws, size_t ws_size,
                              hipStream_t stream) {
  const float* x  = (const float*)d_in[0];
  const float* W  = (const float*)d_in[1];
  const float* gw = (const float*)d_in[2];
  const float* A  = (const float*)d_in[3];
  const float* B  = (const float*)d_in[4];
  float* out = (float*)d_out;

  char* ws = (char*)d_ws;
  unsigned short* Xa  = (unsigned short*)(ws);                  // 8192*2176*2 = 35,651,584
  unsigned short* Wa  = (unsigned short*)(ws + 35651584);       // 2048*2176*2 =  8,912,896
  unsigned short* Ag  = (unsigned short*)(ws + 44564480);       //  128*2048*2 =    524,288
  float*          wte = (float*)        (ws + 45088768);        // 8192*8*4    =    262,144
  // total 45,350,912 bytes

  k_prep<<<3328, 512, 0, stream>>>(x, gw, W, B, A, Xa, wte, Wa, Ag);
  k_ha  <<<512, 256, 0, stream>>>(Xa, Ag, wte, Xa);
  k_gemm<<<1024, 256, 0, stream>>>(Xa, Wa, out);
}